// Round 6
// baseline (864.536 us; speedup 1.0000x reference)
//
#include <hip/hip_runtime.h>
#include <hip/hip_fp16.h>

#define FEAT 64
#define BK   64            // dst nodes per bucket
#define CAP  1536          // bucket capacity (mean 1023, +16 sigma)
#define EPT  8             // edges per thread in scatter
#define MAXB 1024          // >= nbuck (782)

// ---------------------------------------------------------------------------
// K1: xp = x @ W (packed fp16 pairs) ; alpha_src / alpha_dst (fp32)
// Tiled register-blocked GEMM, 64x64 tile per 256-thread block.
// unroll 4 + launch_bounds(256,4): full unroll blew VGPRs to 256 (R3: 100MB
// spill traffic). Alphas computed from fp32 accumulators; only xph is fp16.
// ---------------------------------------------------------------------------
__global__ __launch_bounds__(256, 4) void gemm_alpha_kernel(
    const float* __restrict__ x, const float* __restrict__ W,
    const float* __restrict__ a_src, const float* __restrict__ a_dst,
    unsigned* __restrict__ xph,      // [n*32] packed half2 (feats 2j,2j+1)
    float* __restrict__ as_, float* __restrict__ ad_,
    int n)
{
    __shared__ float XT[FEAT][68];      // XT[k][row]
    __shared__ float Ws[FEAT][FEAT];    // Ws[k][col]

    const int t = threadIdx.x;
    const int row0 = blockIdx.x * 64;

    for (int i = t; i < FEAT * 16; i += 256) {
        const int r = i >> 4, c = (i & 15) << 2;
        *(float4*)(&Ws[r][c]) = *(const float4*)(W + r * FEAT + c);
    }
    for (int i = t; i < 64 * 16; i += 256) {
        const int r = i >> 4, c = (i & 15) << 2;
        const int gr = row0 + r;
        float4 v = make_float4(0.f, 0.f, 0.f, 0.f);
        if (gr < n) v = *(const float4*)(x + (size_t)gr * FEAT + c);
        XT[c + 0][r] = v.x; XT[c + 1][r] = v.y;
        XT[c + 2][r] = v.z; XT[c + 3][r] = v.w;
    }
    __syncthreads();

    const int ni = t >> 4;   // node group (4 nodes)
    const int ci = t & 15;   // col group (4 cols)

    float acc[4][4] = {};
#pragma unroll 4
    for (int k = 0; k < FEAT; ++k) {
        const float4 a = *(const float4*)(&XT[k][ni << 2]);
        const float4 b = *(const float4*)(&Ws[k][ci << 2]);
        acc[0][0] += a.x * b.x; acc[0][1] += a.x * b.y; acc[0][2] += a.x * b.z; acc[0][3] += a.x * b.w;
        acc[1][0] += a.y * b.x; acc[1][1] += a.y * b.y; acc[1][2] += a.y * b.z; acc[1][3] += a.y * b.w;
        acc[2][0] += a.z * b.x; acc[2][1] += a.z * b.y; acc[2][2] += a.z * b.z; acc[2][3] += a.z * b.w;
        acc[3][0] += a.w * b.x; acc[3][1] += a.w * b.y; acc[3][2] += a.w * b.z; acc[3][3] += a.w * b.w;
    }

    const float4 asv = *(const float4*)(a_src + (ci << 2));
    const float4 adv = *(const float4*)(a_dst + (ci << 2));

#pragma unroll
    for (int j = 0; j < 4; ++j) {
        const int node = row0 + (ni << 2) + j;
        if (node < n) {
            __half2 p0 = __floats2half2_rn(acc[j][0], acc[j][1]);
            __half2 p1 = __floats2half2_rn(acc[j][2], acc[j][3]);
            uint2 pk;
            pk.x = *(unsigned*)&p0;
            pk.y = *(unsigned*)&p1;
            *(uint2*)(xph + (size_t)node * 32 + (ci << 1)) = pk;
        }
        float s1 = acc[j][0] * asv.x + acc[j][1] * asv.y + acc[j][2] * asv.z + acc[j][3] * asv.w;
        float s2 = acc[j][0] * adv.x + acc[j][1] * adv.y + acc[j][2] * adv.z + acc[j][3] * adv.w;
#pragma unroll
        for (int o = 8; o > 0; o >>= 1) {
            s1 += __shfl_down(s1, o);
            s2 += __shfl_down(s2, o);
        }
        if (ci == 0 && node < n) { as_[node] = s1; ad_[node] = s2; }
    }
}

// ---------------------------------------------------------------------------
// Bucket scatter: edge -> code (src<<6 | dst&63) into bucket (dst>>6) region.
// LDS histogram per 8192-edge block: ranks via LDS atomics, one global atomic
// per (block,bucket).
// ---------------------------------------------------------------------------
__global__ __launch_bounds__(1024) void bucket_scatter_kernel(
    const int* __restrict__ src, const int* __restrict__ dst,
    int* __restrict__ bcur, unsigned* __restrict__ ebuf, int E, int nbuck)
{
    __shared__ int hist[MAXB];
    __shared__ int base[MAXB];
    const int t = threadIdx.x;
    for (int i = t; i < nbuck; i += 1024) hist[i] = 0;
    __syncthreads();

    unsigned code[EPT];
    int bk[EPT], rk[EPT];
    const int e0 = blockIdx.x * (1024 * EPT) + t;
#pragma unroll
    for (int k = 0; k < EPT; ++k) {
        const int e = e0 + k * 1024;
        bk[k] = -1;
        if (e < E) {
            const int s = src[e], d = dst[e];
            bk[k] = d >> 6;
            code[k] = ((unsigned)s << 6) | (unsigned)(d & 63);
            rk[k] = atomicAdd(&hist[bk[k]], 1);
        }
    }
    __syncthreads();
    for (int i = t; i < nbuck; i += 1024) {
        const int hv = hist[i];
        base[i] = hv ? atomicAdd(&bcur[i], hv) : 0;
    }
    __syncthreads();
#pragma unroll
    for (int k = 0; k < EPT; ++k) {
        if (bk[k] >= 0) {
            const int pos = base[bk[k]] + rk[k];
            if (pos < CAP) ebuf[(size_t)bk[k] * CAP + pos] = code[k];
        }
    }
}

// ---------------------------------------------------------------------------
// Fused aggregate + finalize, block per 64-node bucket, LDS fp32 accumulator.
// R5 failure: 2 edges/wave-iter with serial load->exp->atomic chain = MLP 1,
// VALUBusy 5.5%. Fix: R4-style staging -- each wave stages 64 (code,w) pairs
// (coalesced eb read + scattered as_ gather + exp + denom atomic, all
// amortized), then inner loop processes 8 edges/step with 4 independent
// half2-row gather instructions in flight. LDS atomics staggered (half 0
// even-feat first, half 1 odd-feat first) -> exactly 2-way bank alias = free.
// ---------------------------------------------------------------------------
__global__ __launch_bounds__(512) void gat_aggregate_kernel(
    const int* __restrict__ bcur, const unsigned* __restrict__ ebuf,
    const float* __restrict__ as_, const float* __restrict__ ad_,
    const unsigned* __restrict__ xph, const float* __restrict__ bias,
    float* __restrict__ h, int n)
{
    __shared__ float acc[BK][FEAT];     // 16KB
    __shared__ float denom[BK];
    __shared__ float adb[BK], wself[BK], dinv[BK];
    __shared__ unsigned sh_c[8][64];
    __shared__ float    sh_w[8][64];

    const int b = blockIdx.x;
    const int t = threadIdx.x;
    const int lane = t & 63;
    const int wave = t >> 6;
    const int g0 = b * BK;

    for (int i = t; i < BK * FEAT; i += 512) ((float*)acc)[i] = 0.f;
    if (t < BK) {
        denom[t] = 0.f;
        const int g = g0 + t;
        adb[t] = (g < n) ? ad_[g] : 0.f;
    }
    __syncthreads();

    int cnt = bcur[b];
    if (cnt > CAP) cnt = CAP;
    const unsigned* eb = ebuf + (size_t)b * CAP;

    const int fp   = lane & 31;    // feature-pair index
    const int half = lane >> 5;    // which edge of a pair this lane serves

    for (int base = wave * 64; base < cnt; base += 512) {
        const int m = min(64, cnt - base);

        // ---- stage 64 edges: code + weight (one edge per lane) ----
        const int j = base + lane;
        unsigned code = 0;
        float w = 0.f;
        if (j < cnt) {
            code = eb[j];
            const int s  = code >> 6;
            const int dl = code & 63;
            float tt = as_[s] + adb[dl];
            tt = (tt >= 0.f) ? tt : 0.2f * tt;
            w = __expf(tt);
            atomicAdd(&denom[dl], w);      // folded into staging
        }
        sh_c[wave][lane] = code;
        sh_w[wave][lane] = w;              // wave-private: no barrier needed

        // ---- inner: 8 edges per step, 4 gather instrs in flight ----
        int k = 0;
        for (; k + 8 <= m; k += 8) {
#pragma unroll
            for (int u = 0; u < 4; ++u) {
                const int idx = k + 2 * u + half;
                const unsigned cu = sh_c[wave][idx];
                const float    wu = sh_w[wave][idx];
                const int s  = cu >> 6;
                const int dl = cu & 63;
                const unsigned xv = xph[(size_t)s * 32 + fp];
                const __half2 h2 = *(const __half2*)&xv;
                const float f0 = __low2float(h2)  * wu;   // feat 2fp
                const float f1 = __high2float(h2) * wu;   // feat 2fp+1
                atomicAdd(&acc[dl][2 * fp + half],     half ? f1 : f0);
                atomicAdd(&acc[dl][2 * fp + 1 - half], half ? f0 : f1);
            }
        }
        for (; k < m; k += 2) {
            const int idx = k + half;
            if (idx < m) {
                const unsigned cu = sh_c[wave][idx];
                const float    wu = sh_w[wave][idx];
                const int s  = cu >> 6;
                const int dl = cu & 63;
                const unsigned xv = xph[(size_t)s * 32 + fp];
                const __half2 h2 = *(const __half2*)&xv;
                const float f0 = __low2float(h2)  * wu;
                const float f1 = __high2float(h2) * wu;
                atomicAdd(&acc[dl][2 * fp + half],     half ? f1 : f0);
                atomicAdd(&acc[dl][2 * fp + 1 - half], half ? f0 : f1);
            }
        }
    }
    __syncthreads();

    if (t < BK) {
        const int g = g0 + t;
        float wv = 0.f, dv = 1.f;
        if (g < n) {
            float tt = as_[g] + adb[t];
            tt = (tt >= 0.f) ? tt : 0.2f * tt;
            wv = __expf(tt);
            dv = denom[t] + wv;
        }
        wself[t] = wv;
        dinv[t] = 1.f / dv;
    }
    __syncthreads();

    for (int i = t; i < BK * FEAT; i += 512) {
        const int node = i >> 6, f = i & 63;
        const int g = g0 + node;
        if (g < n) {
            const unsigned u = xph[(size_t)g * 32 + (f >> 1)];
            const __half2 h2 = *(const __half2*)&u;
            const float xs = (f & 1) ? __high2float(h2) : __low2float(h2);
            float v = (acc[node][f] + wself[node] * xs) * dinv[node] + bias[f];
            h[(size_t)g * FEAT + f] = (v > 0.f) ? v : 0.f;
        }
    }
}

// ---------------------------------------------------------------------------
// Pool: batch sorted -> block per graph, binary-search bounds, direct sum.
// ---------------------------------------------------------------------------
__device__ __forceinline__ int lower_bound_i(const int* a, int n, int key)
{
    int lo = 0, hi = n;
    while (lo < hi) {
        const int mid = (lo + hi) >> 1;
        if (a[mid] < key) lo = mid + 1; else hi = mid;
    }
    return lo;
}

__global__ __launch_bounds__(256) void pool_kernel(
    const float* __restrict__ h, const int* __restrict__ batch,
    float* __restrict__ out, int n)
{
    const int g = blockIdx.x;
    const int lane = threadIdx.x & 63;
    const int wave = threadIdx.x >> 6;

    const int lo = lower_bound_i(batch, n, g);
    const int hi = lower_bound_i(batch, n, g + 1);

    float sum = 0.f;
    for (int i = lo + wave; i < hi; i += 4)
        sum += h[(size_t)i * FEAT + lane];

    __shared__ float part[4][FEAT];
    part[wave][lane] = sum;
    __syncthreads();
    if (wave == 0) {
        const float s = part[0][lane] + part[1][lane] + part[2][lane] + part[3][lane];
        const float c = (float)(hi - lo);
        out[(size_t)g * FEAT + lane] = s / fmaxf(c, 1.f);
    }
}

extern "C" void kernel_launch(void* const* d_in, const int* in_sizes, int n_in,
                              void* d_out, int out_size, void* d_ws, size_t ws_size,
                              hipStream_t stream)
{
    const float* x      = (const float*)d_in[0];
    const int*   ei     = (const int*)d_in[1];
    const int*   batch  = (const int*)d_in[2];
    const float* W1     = (const float*)d_in[3];
    const float* asrc1  = (const float*)d_in[4];
    const float* adst1  = (const float*)d_in[5];
    const float* b1     = (const float*)d_in[6];
    const float* W2     = (const float*)d_in[7];
    const float* asrc2  = (const float*)d_in[8];
    const float* adst2  = (const float*)d_in[9];
    const float* b2     = (const float*)d_in[10];

    const int N = in_sizes[2];          // 50000 nodes
    const int E = in_sizes[1] / 2;      // 800000 edges
    const int G = out_size / FEAT;      // 128 graphs

    const int* src = ei;
    const int* dst = ei + E;

    const int nbuck = (N + BK - 1) / BK;   // 782

    // Workspace layout
    float*    ws   = (float*)d_ws;
    unsigned* xph  = (unsigned*)ws;                      // N*32 u32 (fp16 pairs)
    float*    h    = (float*)(xph + (size_t)N * 32);     // N*64 f
    float*    as_  = h + (size_t)N * FEAT;               // N f
    float*    ad_  = as_ + N;                            // N f
    int*      bcur = (int*)(ad_ + N);                    // nbuck i
    unsigned* ebuf = (unsigned*)(bcur + nbuck);          // nbuck*CAP u32

    const int gemmBlocks = (N + 63) / 64;
    const int scatBlocks = (E + 1024 * EPT - 1) / (1024 * EPT);

    // ---- bucketed edge grouping (once; reused by both layers) ----
    hipMemsetAsync(bcur, 0, (size_t)nbuck * sizeof(int), stream);
    bucket_scatter_kernel<<<scatBlocks, 1024, 0, stream>>>(src, dst, bcur, ebuf, E, nbuck);

    // ---- layer 1 ----
    gemm_alpha_kernel<<<gemmBlocks, 256, 0, stream>>>(x, W1, asrc1, adst1, xph, as_, ad_, N);
    gat_aggregate_kernel<<<nbuck, 512, 0, stream>>>(bcur, ebuf, as_, ad_, xph, b1, h, N);

    // ---- layer 2 ----
    gemm_alpha_kernel<<<gemmBlocks, 256, 0, stream>>>(h, W2, asrc2, adst2, xph, as_, ad_, N);
    gat_aggregate_kernel<<<nbuck, 512, 0, stream>>>(bcur, ebuf, as_, ad_, xph, b2, h, N);

    // ---- graph mean pool ----
    pool_kernel<<<G, 256, 0, stream>>>(h, batch, (float*)d_out, N);
}

// Round 7
// 213.868 us; speedup vs baseline: 4.0424x; 4.0424x over previous
//
#include <hip/hip_runtime.h>
#include <hip/hip_fp16.h>

#define FEAT 64
#define BK   64            // dst nodes per bucket
#define CAP  1536          // bucket capacity (mean 1023, +16 sigma)
#define EPT  8             // edges per thread in scatter
#define MAXB 1024          // >= nbuck (782)

// ---------------------------------------------------------------------------
// K1: xp = x @ W (packed fp16 pairs) ; alpha_src / alpha_dst (fp32)
// Tiled register-blocked GEMM, 64x64 tile per 256-thread block.
// unroll 4 + launch_bounds(256,4): full unroll blew VGPRs to 256 (R3: 100MB
// spill traffic). Alphas computed from fp32 accumulators; only xph is fp16.
// ---------------------------------------------------------------------------
__global__ __launch_bounds__(256, 4) void gemm_alpha_kernel(
    const float* __restrict__ x, const float* __restrict__ W,
    const float* __restrict__ a_src, const float* __restrict__ a_dst,
    unsigned* __restrict__ xph,      // [n*32] packed half2 (feats 2j,2j+1)
    float* __restrict__ as_, float* __restrict__ ad_,
    int n)
{
    __shared__ float XT[FEAT][68];      // XT[k][row]
    __shared__ float Ws[FEAT][FEAT];    // Ws[k][col]

    const int t = threadIdx.x;
    const int row0 = blockIdx.x * 64;

    for (int i = t; i < FEAT * 16; i += 256) {
        const int r = i >> 4, c = (i & 15) << 2;
        *(float4*)(&Ws[r][c]) = *(const float4*)(W + r * FEAT + c);
    }
    for (int i = t; i < 64 * 16; i += 256) {
        const int r = i >> 4, c = (i & 15) << 2;
        const int gr = row0 + r;
        float4 v = make_float4(0.f, 0.f, 0.f, 0.f);
        if (gr < n) v = *(const float4*)(x + (size_t)gr * FEAT + c);
        XT[c + 0][r] = v.x; XT[c + 1][r] = v.y;
        XT[c + 2][r] = v.z; XT[c + 3][r] = v.w;
    }
    __syncthreads();

    const int ni = t >> 4;   // node group (4 nodes)
    const int ci = t & 15;   // col group (4 cols)

    float acc[4][4] = {};
#pragma unroll 4
    for (int k = 0; k < FEAT; ++k) {
        const float4 a = *(const float4*)(&XT[k][ni << 2]);
        const float4 b = *(const float4*)(&Ws[k][ci << 2]);
        acc[0][0] += a.x * b.x; acc[0][1] += a.x * b.y; acc[0][2] += a.x * b.z; acc[0][3] += a.x * b.w;
        acc[1][0] += a.y * b.x; acc[1][1] += a.y * b.y; acc[1][2] += a.y * b.z; acc[1][3] += a.y * b.w;
        acc[2][0] += a.z * b.x; acc[2][1] += a.z * b.y; acc[2][2] += a.z * b.z; acc[2][3] += a.z * b.w;
        acc[3][0] += a.w * b.x; acc[3][1] += a.w * b.y; acc[3][2] += a.w * b.z; acc[3][3] += a.w * b.w;
    }

    const float4 asv = *(const float4*)(a_src + (ci << 2));
    const float4 adv = *(const float4*)(a_dst + (ci << 2));

#pragma unroll
    for (int j = 0; j < 4; ++j) {
        const int node = row0 + (ni << 2) + j;
        if (node < n) {
            __half2 p0 = __floats2half2_rn(acc[j][0], acc[j][1]);
            __half2 p1 = __floats2half2_rn(acc[j][2], acc[j][3]);
            uint2 pk;
            pk.x = *(unsigned*)&p0;
            pk.y = *(unsigned*)&p1;
            *(uint2*)(xph + (size_t)node * 32 + (ci << 1)) = pk;
        }
        float s1 = acc[j][0] * asv.x + acc[j][1] * asv.y + acc[j][2] * asv.z + acc[j][3] * asv.w;
        float s2 = acc[j][0] * adv.x + acc[j][1] * adv.y + acc[j][2] * adv.z + acc[j][3] * adv.w;
#pragma unroll
        for (int o = 8; o > 0; o >>= 1) {
            s1 += __shfl_down(s1, o);
            s2 += __shfl_down(s2, o);
        }
        if (ci == 0 && node < n) { as_[node] = s1; ad_[node] = s2; }
    }
}

// ---------------------------------------------------------------------------
// Bucket scatter: edge -> code (src<<6 | dst&63) into bucket (dst>>6) region.
// LDS histogram per 8192-edge block; int atomics only (native, fast).
// ---------------------------------------------------------------------------
__global__ __launch_bounds__(1024) void bucket_scatter_kernel(
    const int* __restrict__ src, const int* __restrict__ dst,
    int* __restrict__ bcur, unsigned* __restrict__ ebuf, int E, int nbuck)
{
    __shared__ int hist[MAXB];
    __shared__ int base[MAXB];
    const int t = threadIdx.x;
    for (int i = t; i < nbuck; i += 1024) hist[i] = 0;
    __syncthreads();

    unsigned code[EPT];
    int bk[EPT], rk[EPT];
    const int e0 = blockIdx.x * (1024 * EPT) + t;
#pragma unroll
    for (int k = 0; k < EPT; ++k) {
        const int e = e0 + k * 1024;
        bk[k] = -1;
        if (e < E) {
            const int s = src[e], d = dst[e];
            bk[k] = d >> 6;
            code[k] = ((unsigned)s << 6) | (unsigned)(d & 63);
            rk[k] = atomicAdd(&hist[bk[k]], 1);
        }
    }
    __syncthreads();
    for (int i = t; i < nbuck; i += 1024) {
        const int hv = hist[i];
        base[i] = hv ? atomicAdd(&bcur[i], hv) : 0;
    }
    __syncthreads();
#pragma unroll
    for (int k = 0; k < EPT; ++k) {
        if (bk[k] >= 0) {
            const int pos = base[bk[k]] + rk[k];
            if (pos < CAP) ebuf[(size_t)bk[k] * CAP + pos] = code[k];
        }
    }
}

// ---------------------------------------------------------------------------
// Fused aggregate + finalize, block per 64-node bucket. NO float atomics:
// R5/R6 identical 359us regardless of ILP => fp32 atomicAdd on LDS compiles
// to a CAS loop (no -munsafe-fp-atomics) and serializes. Instead:
//  1) counting-sort bucket edges by local dst (int LDS atomics, native):
//     histogram -> 64-lane shfl scan -> rank scatter into scode/sw.
//  2) per-node register accumulation: wave owns node; 64 lanes = 32 feature
//     pairs x 2 edge slots; 2 independent accumulator sets -> 2 gathers in
//     flight per half-wave. Self-loop/denom/bias/relu fused; direct h write.
// ---------------------------------------------------------------------------
__global__ __launch_bounds__(512) void gat_aggregate_kernel(
    const int* __restrict__ bcur, const unsigned* __restrict__ ebuf,
    const float* __restrict__ as_, const float* __restrict__ ad_,
    const unsigned* __restrict__ xph, const float* __restrict__ bias,
    float* __restrict__ h, int n)
{
    __shared__ unsigned scode[CAP];     // codes sorted by dl
    __shared__ float    sw[CAP];        // weights, same order
    __shared__ int hist[BK];
    __shared__ int starts[BK + 1];
    __shared__ int cur[BK];
    __shared__ float adb[BK];

    const int b = blockIdx.x;
    const int t = threadIdx.x;
    const int lane = t & 63;
    const int wave = t >> 6;
    const int g0 = b * BK;

    if (t < BK) {
        hist[t] = 0;
        const int g = g0 + t;
        adb[t] = (g < n) ? ad_[g] : 0.f;
    }
    __syncthreads();

    int cnt = bcur[b];
    if (cnt > CAP) cnt = CAP;
    const unsigned* eb = ebuf + (size_t)b * CAP;

    // phase 1: histogram of local dst (native int LDS atomics)
    for (int i = t; i < cnt; i += 512)
        atomicAdd(&hist[eb[i] & 63], 1);
    __syncthreads();

    // phase 2: exclusive scan of 64 bins (one wave, shfl inclusive scan)
    if (wave == 0) {
        int v = hist[lane];
#pragma unroll
        for (int o = 1; o < 64; o <<= 1) {
            const int u = __shfl_up(v, o);
            if (lane >= o) v += u;
        }
        starts[lane + 1] = v;
        cur[lane] = v - hist[lane];
        if (lane == 0) starts[0] = 0;
    }
    __syncthreads();

    // phase 3: rank & scatter into LDS, computing edge weight once
    for (int i = t; i < cnt; i += 512) {
        const unsigned c = eb[i];
        const int s = c >> 6, dl = c & 63;
        float tt = as_[s] + adb[dl];
        tt = (tt >= 0.f) ? tt : 0.2f * tt;
        const float w = __expf(tt);
        const int pos = atomicAdd(&cur[dl], 1);   // int atomic: native
        scode[pos] = c;
        sw[pos] = w;
    }
    __syncthreads();

    // phase 4: per-node accumulation, register-only
    const int fp   = lane & 31;    // feature-pair index
    const int half = lane >> 5;    // edge slot (even/odd)

    for (int node = wave; node < BK; node += 8) {
        const int g = g0 + node;
        if (g >= n) continue;
        const int st = starts[node], en = starts[node + 1];

        float a0 = 0.f, a1 = 0.f, b0 = 0.f, b1 = 0.f;
        float ws0 = 0.f, ws1 = 0.f;

        int i = st + half;
        // 2 edges per half in flight (independent acc sets)
        for (; i + 2 < en; i += 4) {
            const unsigned c0 = scode[i];
            const unsigned c1 = scode[i + 2];
            const float w0 = sw[i];
            const float w1 = sw[i + 2];
            const unsigned xv0 = xph[(size_t)(c0 >> 6) * 32 + fp];
            const unsigned xv1 = xph[(size_t)(c1 >> 6) * 32 + fp];
            const __half2 h0 = *(const __half2*)&xv0;
            const __half2 h1 = *(const __half2*)&xv1;
            a0 += w0 * __low2float(h0);  a1 += w0 * __high2float(h0);
            b0 += w1 * __low2float(h1);  b1 += w1 * __high2float(h1);
            ws0 += w0; ws1 += w1;
        }
        for (; i < en; i += 2) {
            const unsigned c0 = scode[i];
            const float w0 = sw[i];
            const unsigned xv0 = xph[(size_t)(c0 >> 6) * 32 + fp];
            const __half2 h0 = *(const __half2*)&xv0;
            a0 += w0 * __low2float(h0);  a1 += w0 * __high2float(h0);
            ws0 += w0;
        }
        a0 += b0; a1 += b1;
        float wsum = ws0 + ws1;

        // combine the two halves (each edge counted exactly once overall)
        a0   += __shfl_xor(a0, 32);
        a1   += __shfl_xor(a1, 32);
        wsum += __shfl_xor(wsum, 32);

        // self-loop + normalize + bias + relu
        float tt = as_[g] + adb[node];
        tt = (tt >= 0.f) ? tt : 0.2f * tt;
        const float wself = __expf(tt);
        const unsigned xvg = xph[(size_t)g * 32 + fp];
        const __half2 hg = *(const __half2*)&xvg;
        const float dinv = 1.f / (wsum + wself);
        float v0 = (a0 + wself * __low2float(hg))  * dinv + bias[2 * fp];
        float v1 = (a1 + wself * __high2float(hg)) * dinv + bias[2 * fp + 1];
        v0 = fmaxf(v0, 0.f);
        v1 = fmaxf(v1, 0.f);
        if (half == 0)
            *(float2*)(h + (size_t)g * FEAT + 2 * fp) = make_float2(v0, v1);
    }
}

// ---------------------------------------------------------------------------
// Pool: batch sorted -> block per graph, binary-search bounds, direct sum.
// ---------------------------------------------------------------------------
__device__ __forceinline__ int lower_bound_i(const int* a, int n, int key)
{
    int lo = 0, hi = n;
    while (lo < hi) {
        const int mid = (lo + hi) >> 1;
        if (a[mid] < key) lo = mid + 1; else hi = mid;
    }
    return lo;
}

__global__ __launch_bounds__(256) void pool_kernel(
    const float* __restrict__ h, const int* __restrict__ batch,
    float* __restrict__ out, int n)
{
    const int g = blockIdx.x;
    const int lane = threadIdx.x & 63;
    const int wave = threadIdx.x >> 6;

    const int lo = lower_bound_i(batch, n, g);
    const int hi = lower_bound_i(batch, n, g + 1);

    float sum = 0.f;
    for (int i = lo + wave; i < hi; i += 4)
        sum += h[(size_t)i * FEAT + lane];

    __shared__ float part[4][FEAT];
    part[wave][lane] = sum;
    __syncthreads();
    if (wave == 0) {
        const float s = part[0][lane] + part[1][lane] + part[2][lane] + part[3][lane];
        const float c = (float)(hi - lo);
        out[(size_t)g * FEAT + lane] = s / fmaxf(c, 1.f);
    }
}

extern "C" void kernel_launch(void* const* d_in, const int* in_sizes, int n_in,
                              void* d_out, int out_size, void* d_ws, size_t ws_size,
                              hipStream_t stream)
{
    const float* x      = (const float*)d_in[0];
    const int*   ei     = (const int*)d_in[1];
    const int*   batch  = (const int*)d_in[2];
    const float* W1     = (const float*)d_in[3];
    const float* asrc1  = (const float*)d_in[4];
    const float* adst1  = (const float*)d_in[5];
    const float* b1     = (const float*)d_in[6];
    const float* W2     = (const float*)d_in[7];
    const float* asrc2  = (const float*)d_in[8];
    const float* adst2  = (const float*)d_in[9];
    const float* b2     = (const float*)d_in[10];

    const int N = in_sizes[2];          // 50000 nodes
    const int E = in_sizes[1] / 2;      // 800000 edges
    const int G = out_size / FEAT;      // 128 graphs

    const int* src = ei;
    const int* dst = ei + E;

    const int nbuck = (N + BK - 1) / BK;   // 782

    // Workspace layout
    float*    ws   = (float*)d_ws;
    unsigned* xph  = (unsigned*)ws;                      // N*32 u32 (fp16 pairs)
    float*    h    = (float*)(xph + (size_t)N * 32);     // N*64 f
    float*    as_  = h + (size_t)N * FEAT;               // N f
    float*    ad_  = as_ + N;                            // N f
    int*      bcur = (int*)(ad_ + N);                    // nbuck i
    unsigned* ebuf = (unsigned*)(bcur + nbuck);          // nbuck*CAP u32

    const int gemmBlocks = (N + 63) / 64;
    const int scatBlocks = (E + 1024 * EPT - 1) / (1024 * EPT);

    // ---- bucketed edge grouping (once; reused by both layers) ----
    hipMemsetAsync(bcur, 0, (size_t)nbuck * sizeof(int), stream);
    bucket_scatter_kernel<<<scatBlocks, 1024, 0, stream>>>(src, dst, bcur, ebuf, E, nbuck);

    // ---- layer 1 ----
    gemm_alpha_kernel<<<gemmBlocks, 256, 0, stream>>>(x, W1, asrc1, adst1, xph, as_, ad_, N);
    gat_aggregate_kernel<<<nbuck, 512, 0, stream>>>(bcur, ebuf, as_, ad_, xph, b1, h, N);

    // ---- layer 2 ----
    gemm_alpha_kernel<<<gemmBlocks, 256, 0, stream>>>(h, W2, asrc2, adst2, xph, as_, ad_, N);
    gat_aggregate_kernel<<<nbuck, 512, 0, stream>>>(bcur, ebuf, as_, ad_, xph, b2, h, N);

    // ---- graph mean pool ----
    pool_kernel<<<G, 256, 0, stream>>>(h, batch, (float*)d_out, N);
}

// Round 8
// 210.981 us; speedup vs baseline: 4.0977x; 1.0137x over previous
//
#include <hip/hip_runtime.h>
#include <hip/hip_fp16.h>

#define FEAT 64
#define BK   64            // dst nodes per bucket
#define CAP  1536          // bucket capacity (mean 1023, +16 sigma)
#define EPT  8             // edges per thread in scatter
#define MAXB 1024          // >= nbuck (782)

// ---------------------------------------------------------------------------
// K1: xp = x @ W (packed fp16 pairs) ; alpha_src / alpha_dst (fp32)
// Tiled register-blocked GEMM, 64x64 tile per 256-thread block.
// unroll 4 + launch_bounds(256,4): full unroll blew VGPRs to 256 (R3: 100MB
// spill traffic). Alphas computed from fp32 accumulators; only xph is fp16.
// ---------------------------------------------------------------------------
__global__ __launch_bounds__(256, 4) void gemm_alpha_kernel(
    const float* __restrict__ x, const float* __restrict__ W,
    const float* __restrict__ a_src, const float* __restrict__ a_dst,
    unsigned* __restrict__ xph,      // [n*32] packed half2 (feats 2j,2j+1)
    float* __restrict__ as_, float* __restrict__ ad_,
    int n)
{
    __shared__ float XT[FEAT][68];      // XT[k][row]
    __shared__ float Ws[FEAT][FEAT];    // Ws[k][col]

    const int t = threadIdx.x;
    const int row0 = blockIdx.x * 64;

    for (int i = t; i < FEAT * 16; i += 256) {
        const int r = i >> 4, c = (i & 15) << 2;
        *(float4*)(&Ws[r][c]) = *(const float4*)(W + r * FEAT + c);
    }
    for (int i = t; i < 64 * 16; i += 256) {
        const int r = i >> 4, c = (i & 15) << 2;
        const int gr = row0 + r;
        float4 v = make_float4(0.f, 0.f, 0.f, 0.f);
        if (gr < n) v = *(const float4*)(x + (size_t)gr * FEAT + c);
        XT[c + 0][r] = v.x; XT[c + 1][r] = v.y;
        XT[c + 2][r] = v.z; XT[c + 3][r] = v.w;
    }
    __syncthreads();

    const int ni = t >> 4;   // node group (4 nodes)
    const int ci = t & 15;   // col group (4 cols)

    float acc[4][4] = {};
#pragma unroll 4
    for (int k = 0; k < FEAT; ++k) {
        const float4 a = *(const float4*)(&XT[k][ni << 2]);
        const float4 b = *(const float4*)(&Ws[k][ci << 2]);
        acc[0][0] += a.x * b.x; acc[0][1] += a.x * b.y; acc[0][2] += a.x * b.z; acc[0][3] += a.x * b.w;
        acc[1][0] += a.y * b.x; acc[1][1] += a.y * b.y; acc[1][2] += a.y * b.z; acc[1][3] += a.y * b.w;
        acc[2][0] += a.z * b.x; acc[2][1] += a.z * b.y; acc[2][2] += a.z * b.z; acc[2][3] += a.z * b.w;
        acc[3][0] += a.w * b.x; acc[3][1] += a.w * b.y; acc[3][2] += a.w * b.z; acc[3][3] += a.w * b.w;
    }

    const float4 asv = *(const float4*)(a_src + (ci << 2));
    const float4 adv = *(const float4*)(a_dst + (ci << 2));

#pragma unroll
    for (int j = 0; j < 4; ++j) {
        const int node = row0 + (ni << 2) + j;
        if (node < n) {
            __half2 p0 = __floats2half2_rn(acc[j][0], acc[j][1]);
            __half2 p1 = __floats2half2_rn(acc[j][2], acc[j][3]);
            uint2 pk;
            pk.x = *(unsigned*)&p0;
            pk.y = *(unsigned*)&p1;
            *(uint2*)(xph + (size_t)node * 32 + (ci << 1)) = pk;
        }
        float s1 = acc[j][0] * asv.x + acc[j][1] * asv.y + acc[j][2] * asv.z + acc[j][3] * asv.w;
        float s2 = acc[j][0] * adv.x + acc[j][1] * adv.y + acc[j][2] * adv.z + acc[j][3] * adv.w;
#pragma unroll
        for (int o = 8; o > 0; o >>= 1) {
            s1 += __shfl_down(s1, o);
            s2 += __shfl_down(s2, o);
        }
        if (ci == 0 && node < n) { as_[node] = s1; ad_[node] = s2; }
    }
}

// ---------------------------------------------------------------------------
// Bucket scatter: edge -> code (src<<6 | dst&63) into bucket (dst>>6) region.
// LDS histogram per 8192-edge block; int atomics only (native, fast).
// ---------------------------------------------------------------------------
__global__ __launch_bounds__(1024) void bucket_scatter_kernel(
    const int* __restrict__ src, const int* __restrict__ dst,
    int* __restrict__ bcur, unsigned* __restrict__ ebuf, int E, int nbuck)
{
    __shared__ int hist[MAXB];
    __shared__ int base[MAXB];
    const int t = threadIdx.x;
    for (int i = t; i < nbuck; i += 1024) hist[i] = 0;
    __syncthreads();

    unsigned code[EPT];
    int bk[EPT], rk[EPT];
    const int e0 = blockIdx.x * (1024 * EPT) + t;
#pragma unroll
    for (int k = 0; k < EPT; ++k) {
        const int e = e0 + k * 1024;
        bk[k] = -1;
        if (e < E) {
            const int s = src[e], d = dst[e];
            bk[k] = d >> 6;
            code[k] = ((unsigned)s << 6) | (unsigned)(d & 63);
            rk[k] = atomicAdd(&hist[bk[k]], 1);
        }
    }
    __syncthreads();
    for (int i = t; i < nbuck; i += 1024) {
        const int hv = hist[i];
        base[i] = hv ? atomicAdd(&bcur[i], hv) : 0;
    }
    __syncthreads();
#pragma unroll
    for (int k = 0; k < EPT; ++k) {
        if (bk[k] >= 0) {
            const int pos = base[bk[k]] + rk[k];
            if (pos < CAP) ebuf[(size_t)bk[k] * CAP + pos] = code[k];
        }
    }
}

// ---------------------------------------------------------------------------
// Fused aggregate + finalize, block per 64-node bucket. No float atomics
// (R6: fp32 LDS atomicAdd = CAS loop, 359us flat regardless of ILP).
//  1) counting-sort bucket edges by local dst (native int LDS atomics).
//  2) per-node register accumulation. R7 kept only 2 gathers in flight per
//     wave (32-lane 4B loads) -> latency-exposed. Now: 16 lanes x 4 edge
//     slots, 8B uint2 loads (4 feats/lane) -> one instr fetches 4 edge rows,
//     4 independent instrs per step = 16 rows in flight per wave. Avg degree
//     16 -> typical node done in one step. Cross-slot combine via shfl_xor.
// ---------------------------------------------------------------------------
__global__ __launch_bounds__(512) void gat_aggregate_kernel(
    const int* __restrict__ bcur, const unsigned* __restrict__ ebuf,
    const float* __restrict__ as_, const float* __restrict__ ad_,
    const uint2* __restrict__ xph2,   // [n*16] uint2 = 4 packed fp16 feats
    const float* __restrict__ bias,
    float* __restrict__ h, int n)
{
    __shared__ unsigned scode[CAP];     // codes sorted by dl
    __shared__ float    sw[CAP];        // weights, same order
    __shared__ int hist[BK];
    __shared__ int starts[BK + 1];
    __shared__ int cur[BK];
    __shared__ float adb[BK];

    const int b = blockIdx.x;
    const int t = threadIdx.x;
    const int lane = t & 63;
    const int wave = t >> 6;
    const int g0 = b * BK;

    if (t < BK) {
        hist[t] = 0;
        const int g = g0 + t;
        adb[t] = (g < n) ? ad_[g] : 0.f;
    }
    __syncthreads();

    int cnt = bcur[b];
    if (cnt > CAP) cnt = CAP;
    const unsigned* eb = ebuf + (size_t)b * CAP;

    // phase 1: histogram of local dst (native int LDS atomics)
    for (int i = t; i < cnt; i += 512)
        atomicAdd(&hist[eb[i] & 63], 1);
    __syncthreads();

    // phase 2: exclusive scan of 64 bins (one wave, shfl inclusive scan)
    if (wave == 0) {
        int v = hist[lane];
#pragma unroll
        for (int o = 1; o < 64; o <<= 1) {
            const int u = __shfl_up(v, o);
            if (lane >= o) v += u;
        }
        starts[lane + 1] = v;
        cur[lane] = v - hist[lane];
        if (lane == 0) starts[0] = 0;
    }
    __syncthreads();

    // phase 3: rank & scatter into LDS, computing edge weight once
    for (int i = t; i < cnt; i += 512) {
        const unsigned c = eb[i];
        const int s = c >> 6, dl = c & 63;
        float tt = as_[s] + adb[dl];
        tt = (tt >= 0.f) ? tt : 0.2f * tt;
        const float w = __expf(tt);
        const int pos = atomicAdd(&cur[dl], 1);   // int atomic: native
        scode[pos] = c;
        sw[pos] = w;
    }
    __syncthreads();

    // phase 4: per-node accumulation, register-only.
    const int q  = lane >> 4;      // edge slot 0..3
    const int fq = lane & 15;      // feature quad: feats 4fq..4fq+3

    for (int node = wave; node < BK; node += 8) {
        const int g = g0 + node;
        if (g >= n) continue;
        const int st = starts[node], en = starts[node + 1];

        float a0 = 0.f, a1 = 0.f, a2 = 0.f, a3 = 0.f;
        float wsum = 0.f;

        int i = st + q;
        // main: 4 independent uint2 gathers (16 edge rows in flight/wave)
        for (; i + 12 < en; i += 16) {
            const unsigned c0 = scode[i];
            const unsigned c1 = scode[i + 4];
            const unsigned c2 = scode[i + 8];
            const unsigned c3 = scode[i + 12];
            const float w0 = sw[i], w1 = sw[i + 4], w2 = sw[i + 8], w3 = sw[i + 12];
            const uint2 x0 = xph2[(size_t)(c0 >> 6) * 16 + fq];
            const uint2 x1 = xph2[(size_t)(c1 >> 6) * 16 + fq];
            const uint2 x2 = xph2[(size_t)(c2 >> 6) * 16 + fq];
            const uint2 x3 = xph2[(size_t)(c3 >> 6) * 16 + fq];
            const __half2 l0 = *(const __half2*)&x0.x, h0 = *(const __half2*)&x0.y;
            const __half2 l1 = *(const __half2*)&x1.x, h1 = *(const __half2*)&x1.y;
            const __half2 l2 = *(const __half2*)&x2.x, h2 = *(const __half2*)&x2.y;
            const __half2 l3 = *(const __half2*)&x3.x, h3 = *(const __half2*)&x3.y;
            a0 += w0 * __low2float(l0) + w1 * __low2float(l1)
                + w2 * __low2float(l2) + w3 * __low2float(l3);
            a1 += w0 * __high2float(l0) + w1 * __high2float(l1)
                + w2 * __high2float(l2) + w3 * __high2float(l3);
            a2 += w0 * __low2float(h0) + w1 * __low2float(h1)
                + w2 * __low2float(h2) + w3 * __low2float(h3);
            a3 += w0 * __high2float(h0) + w1 * __high2float(h1)
                + w2 * __high2float(h2) + w3 * __high2float(h3);
            wsum += (w0 + w1) + (w2 + w3);
        }
        // tail: this slot's residue class
        for (; i < en; i += 4) {
            const unsigned c0 = scode[i];
            const float w0 = sw[i];
            const uint2 x0 = xph2[(size_t)(c0 >> 6) * 16 + fq];
            const __half2 l0 = *(const __half2*)&x0.x, h0 = *(const __half2*)&x0.y;
            a0 += w0 * __low2float(l0);
            a1 += w0 * __high2float(l0);
            a2 += w0 * __low2float(h0);
            a3 += w0 * __high2float(h0);
            wsum += w0;
        }

        // combine the 4 edge slots (xor across lane bits 4,5)
        a0   += __shfl_xor(a0, 16);   a0   += __shfl_xor(a0, 32);
        a1   += __shfl_xor(a1, 16);   a1   += __shfl_xor(a1, 32);
        a2   += __shfl_xor(a2, 16);   a2   += __shfl_xor(a2, 32);
        a3   += __shfl_xor(a3, 16);   a3   += __shfl_xor(a3, 32);
        wsum += __shfl_xor(wsum, 16); wsum += __shfl_xor(wsum, 32);

        // self-loop + normalize + bias + relu; slot-0 lanes write float4
        float tt = as_[g] + adb[node];
        tt = (tt >= 0.f) ? tt : 0.2f * tt;
        const float wself = __expf(tt);
        const uint2 xg = xph2[(size_t)g * 16 + fq];
        const __half2 gl = *(const __half2*)&xg.x, gh = *(const __half2*)&xg.y;
        const float dinv = 1.f / (wsum + wself);
        const float4 b4 = *(const float4*)(bias + 4 * fq);
        float4 v;
        v.x = fmaxf((a0 + wself * __low2float(gl))  * dinv + b4.x, 0.f);
        v.y = fmaxf((a1 + wself * __high2float(gl)) * dinv + b4.y, 0.f);
        v.z = fmaxf((a2 + wself * __low2float(gh))  * dinv + b4.z, 0.f);
        v.w = fmaxf((a3 + wself * __high2float(gh)) * dinv + b4.w, 0.f);
        if (q == 0)
            *(float4*)(h + (size_t)g * FEAT + 4 * fq) = v;
    }
}

// ---------------------------------------------------------------------------
// Pool: batch sorted -> block per graph, binary-search bounds, direct sum.
// ---------------------------------------------------------------------------
__device__ __forceinline__ int lower_bound_i(const int* a, int n, int key)
{
    int lo = 0, hi = n;
    while (lo < hi) {
        const int mid = (lo + hi) >> 1;
        if (a[mid] < key) lo = mid + 1; else hi = mid;
    }
    return lo;
}

__global__ __launch_bounds__(256) void pool_kernel(
    const float* __restrict__ h, const int* __restrict__ batch,
    float* __restrict__ out, int n)
{
    const int g = blockIdx.x;
    const int lane = threadIdx.x & 63;
    const int wave = threadIdx.x >> 6;

    const int lo = lower_bound_i(batch, n, g);
    const int hi = lower_bound_i(batch, n, g + 1);

    float sum = 0.f;
    for (int i = lo + wave; i < hi; i += 4)
        sum += h[(size_t)i * FEAT + lane];

    __shared__ float part[4][FEAT];
    part[wave][lane] = sum;
    __syncthreads();
    if (wave == 0) {
        const float s = part[0][lane] + part[1][lane] + part[2][lane] + part[3][lane];
        const float c = (float)(hi - lo);
        out[(size_t)g * FEAT + lane] = s / fmaxf(c, 1.f);
    }
}

extern "C" void kernel_launch(void* const* d_in, const int* in_sizes, int n_in,
                              void* d_out, int out_size, void* d_ws, size_t ws_size,
                              hipStream_t stream)
{
    const float* x      = (const float*)d_in[0];
    const int*   ei     = (const int*)d_in[1];
    const int*   batch  = (const int*)d_in[2];
    const float* W1     = (const float*)d_in[3];
    const float* asrc1  = (const float*)d_in[4];
    const float* adst1  = (const float*)d_in[5];
    const float* b1     = (const float*)d_in[6];
    const float* W2     = (const float*)d_in[7];
    const float* asrc2  = (const float*)d_in[8];
    const float* adst2  = (const float*)d_in[9];
    const float* b2     = (const float*)d_in[10];

    const int N = in_sizes[2];          // 50000 nodes
    const int E = in_sizes[1] / 2;      // 800000 edges
    const int G = out_size / FEAT;      // 128 graphs

    const int* src = ei;
    const int* dst = ei + E;

    const int nbuck = (N + BK - 1) / BK;   // 782

    // Workspace layout
    float*    ws   = (float*)d_ws;
    unsigned* xph  = (unsigned*)ws;                      // N*32 u32 (fp16 pairs)
    float*    h    = (float*)(xph + (size_t)N * 32);     // N*64 f
    float*    as_  = h + (size_t)N * FEAT;               // N f
    float*    ad_  = as_ + N;                            // N f
    int*      bcur = (int*)(ad_ + N);                    // nbuck i
    unsigned* ebuf = (unsigned*)(bcur + nbuck);          // nbuck*CAP u32

    const int gemmBlocks = (N + 63) / 64;
    const int scatBlocks = (E + 1024 * EPT - 1) / (1024 * EPT);

    // ---- bucketed edge grouping (once; reused by both layers) ----
    hipMemsetAsync(bcur, 0, (size_t)nbuck * sizeof(int), stream);
    bucket_scatter_kernel<<<scatBlocks, 1024, 0, stream>>>(src, dst, bcur, ebuf, E, nbuck);

    // ---- layer 1 ----
    gemm_alpha_kernel<<<gemmBlocks, 256, 0, stream>>>(x, W1, asrc1, adst1, xph, as_, ad_, N);
    gat_aggregate_kernel<<<nbuck, 512, 0, stream>>>(bcur, ebuf, as_, ad_,
                                                    (const uint2*)xph, b1, h, N);

    // ---- layer 2 ----
    gemm_alpha_kernel<<<gemmBlocks, 256, 0, stream>>>(h, W2, asrc2, adst2, xph, as_, ad_, N);
    gat_aggregate_kernel<<<nbuck, 512, 0, stream>>>(bcur, ebuf, as_, ad_,
                                                    (const uint2*)xph, b2, h, N);

    // ---- graph mean pool ----
    pool_kernel<<<G, 256, 0, stream>>>(h, batch, (float*)d_out, N);
}

// Round 9
// 204.173 us; speedup vs baseline: 4.2343x; 1.0333x over previous
//
#include <hip/hip_runtime.h>
#include <hip/hip_fp16.h>

#define FEAT 64
#define BK   64            // dst nodes per bucket
#define CAP  1536          // bucket capacity (mean 1023, +16 sigma)
#define EPT  4             // edges per thread in scatter (R8: 8 -> 98 blocks, CUs idle)
#define MAXB 1024          // >= nbuck (782)

typedef _Float16 f16;
typedef __attribute__((ext_vector_type(8))) _Float16 f16x8;
typedef __attribute__((ext_vector_type(4))) float    f32x4;

// ---------------------------------------------------------------------------
// K1: xp = x @ W via MFMA f16 (fp32 accumulate); alphas fp32.
// Block = 256 thr = 4 waves; block tile 64 rows x 64 cols, K=64.
// Wave w: rows w*16..w*16+15, all 64 cols as 4 n-tiles of 16x16x32 MFMA x2 K.
// A[m=lane&15][k=(lane>>4)*8+j], B[n=lane&15][k=(lane>>4)*8+j] (m120 layout),
// C/D col=lane&15, row=(lane>>4)*4+reg (m89-verified).
// LDS rows padded to 72 f16 (144B = 9x16B): m-stride bank quad = m*4 mod 32
// -> 2-way alias = free. Epilogue: C tile -> wave-private LDS -> xph pack +
// alpha dot-products (no barrier: same-wave LDS ordering via lgkmcnt).
// ---------------------------------------------------------------------------
__global__ __launch_bounds__(256) void gemm_alpha_kernel(
    const float* __restrict__ x, const float* __restrict__ W,
    const float* __restrict__ a_src, const float* __restrict__ a_dst,
    unsigned* __restrict__ xph,      // [n*32] packed half2 (feats 2j,2j+1)
    float* __restrict__ as_, float* __restrict__ ad_,
    int n)
{
    __shared__ __align__(16) f16 Xs[64][72];   // [m][k]
    __shared__ __align__(16) f16 Wt[64][72];   // [n][k] (W transposed)
    __shared__ float Cs[4][16][68];            // per-wave C staging
    __shared__ float asl[64], adl[64];

    const int t = threadIdx.x;
    const int lane = t & 63;
    const int wave = t >> 6;
    const int row0 = blockIdx.x * 64;

    if (t < 64) asl[t] = a_src[t];
    else if (t < 128) adl[t - 64] = a_dst[t - 64];

    // stage x -> f16
    for (int i = t; i < 64 * 16; i += 256) {
        const int r = i >> 4, c4 = (i & 15) << 2;
        const int gr = row0 + r;
        float4 v = make_float4(0.f, 0.f, 0.f, 0.f);
        if (gr < n) v = *(const float4*)(x + (size_t)gr * FEAT + c4);
        Xs[r][c4 + 0] = (f16)v.x; Xs[r][c4 + 1] = (f16)v.y;
        Xs[r][c4 + 2] = (f16)v.z; Xs[r][c4 + 3] = (f16)v.w;
    }
    // stage W transposed -> f16
    for (int i = t; i < 64 * 16; i += 256) {
        const int k = i >> 4, c4 = (i & 15) << 2;
        const float4 v = *(const float4*)(W + k * FEAT + c4);
        Wt[c4 + 0][k] = (f16)v.x; Wt[c4 + 1][k] = (f16)v.y;
        Wt[c4 + 2][k] = (f16)v.z; Wt[c4 + 3][k] = (f16)v.w;
    }
    __syncthreads();

    const int mrow = (wave << 4) + (lane & 15);
    const int kg = lane >> 4;
    const f16x8 a0 = *(const f16x8*)(&Xs[mrow][kg * 8]);
    const f16x8 a1 = *(const f16x8*)(&Xs[mrow][32 + kg * 8]);

    f32x4 acc[4];
#pragma unroll
    for (int tile = 0; tile < 4; ++tile) {
        const int ncol = tile * 16 + (lane & 15);
        const f16x8 b0 = *(const f16x8*)(&Wt[ncol][kg * 8]);
        const f16x8 b1 = *(const f16x8*)(&Wt[ncol][32 + kg * 8]);
        f32x4 c = {0.f, 0.f, 0.f, 0.f};
        c = __builtin_amdgcn_mfma_f32_16x16x32_f16(a0, b0, c, 0, 0, 0);
        c = __builtin_amdgcn_mfma_f32_16x16x32_f16(a1, b1, c, 0, 0, 0);
        acc[tile] = c;
    }

    // C -> wave-private LDS
#pragma unroll
    for (int tile = 0; tile < 4; ++tile)
#pragma unroll
        for (int reg = 0; reg < 4; ++reg)
            Cs[wave][(lane >> 4) * 4 + reg][tile * 16 + (lane & 15)] = acc[tile][reg];

    // xph pack: 16 rows x 32 pairs per wave
    for (int i = lane; i < 16 * 32; i += 64) {
        const int r = i >> 5, fp = i & 31;
        const int node = row0 + (wave << 4) + r;
        if (node < n) {
            const __half2 p = __floats2half2_rn(Cs[wave][r][2 * fp], Cs[wave][r][2 * fp + 1]);
            xph[(size_t)node * 32 + fp] = *(const unsigned*)&p;
        }
    }

    // alphas: lane -> (row = lane>>2, quarter = lane&3 covering 16 cols)
    {
        const int r = lane >> 2, q = lane & 3;
        float s1 = 0.f, s2 = 0.f;
#pragma unroll
        for (int j = 0; j < 16; ++j) {
            const int c = q * 16 + j;
            const float v = Cs[wave][r][c];
            s1 += v * asl[c];
            s2 += v * adl[c];
        }
        s1 += __shfl_xor(s1, 1); s1 += __shfl_xor(s1, 2);
        s2 += __shfl_xor(s2, 1); s2 += __shfl_xor(s2, 2);
        const int node = row0 + (wave << 4) + r;
        if (q == 0 && node < n) { as_[node] = s1; ad_[node] = s2; }
    }
}

// ---------------------------------------------------------------------------
// Bucket scatter: edge -> code (src<<6 | dst&63) into bucket (dst>>6) region.
// ---------------------------------------------------------------------------
__global__ __launch_bounds__(1024) void bucket_scatter_kernel(
    const int* __restrict__ src, const int* __restrict__ dst,
    int* __restrict__ bcur, unsigned* __restrict__ ebuf, int E, int nbuck)
{
    __shared__ int hist[MAXB];
    __shared__ int base[MAXB];
    const int t = threadIdx.x;
    for (int i = t; i < nbuck; i += 1024) hist[i] = 0;
    __syncthreads();

    unsigned code[EPT];
    int bk[EPT], rk[EPT];
    const int e0 = blockIdx.x * (1024 * EPT) + t;
#pragma unroll
    for (int k = 0; k < EPT; ++k) {
        const int e = e0 + k * 1024;
        bk[k] = -1;
        if (e < E) {
            const int s = src[e], d = dst[e];
            bk[k] = d >> 6;
            code[k] = ((unsigned)s << 6) | (unsigned)(d & 63);
            rk[k] = atomicAdd(&hist[bk[k]], 1);
        }
    }
    __syncthreads();
    for (int i = t; i < nbuck; i += 1024) {
        const int hv = hist[i];
        base[i] = hv ? atomicAdd(&bcur[i], hv) : 0;
    }
    __syncthreads();
#pragma unroll
    for (int k = 0; k < EPT; ++k) {
        if (bk[k] >= 0) {
            const int pos = base[bk[k]] + rk[k];
            if (pos < CAP) ebuf[(size_t)bk[k] * CAP + pos] = code[k];
        }
    }
}

// ---------------------------------------------------------------------------
// Bucket sort (ONCE per call): counting-sort each bucket's codes by local dst,
// in place; starts -> global. Hoists R8's aggregate phases 1-3 out of the
// per-layer path (they were paid twice).
// ---------------------------------------------------------------------------
__global__ __launch_bounds__(512) void bucket_sort_kernel(
    const int* __restrict__ bcur, unsigned* __restrict__ ebuf,
    int* __restrict__ startsG)
{
    __shared__ unsigned scode[CAP];
    __shared__ int hist[BK];
    __shared__ int starts[BK + 1];
    __shared__ int cur[BK];

    const int b = blockIdx.x;
    const int t = threadIdx.x;
    const int lane = t & 63;
    const int wave = t >> 6;

    if (t < BK) hist[t] = 0;
    __syncthreads();

    int cnt = bcur[b];
    if (cnt > CAP) cnt = CAP;
    unsigned* eb = ebuf + (size_t)b * CAP;

    // read (<=3 per thread) + histogram; all reads precede all writes
    const int i0 = t, i1 = t + 512, i2 = t + 1024;
    unsigned c0 = 0, c1 = 0, c2 = 0;
    if (i0 < cnt) { c0 = eb[i0]; atomicAdd(&hist[c0 & 63], 1); }
    if (i1 < cnt) { c1 = eb[i1]; atomicAdd(&hist[c1 & 63], 1); }
    if (i2 < cnt) { c2 = eb[i2]; atomicAdd(&hist[c2 & 63], 1); }
    __syncthreads();

    if (wave == 0) {
        int v = hist[lane];
#pragma unroll
        for (int o = 1; o < 64; o <<= 1) {
            const int u = __shfl_up(v, o);
            if (lane >= o) v += u;
        }
        starts[lane + 1] = v;
        cur[lane] = v - hist[lane];
        if (lane == 0) starts[0] = 0;
    }
    __syncthreads();

    if (i0 < cnt) { const int p = atomicAdd(&cur[c0 & 63], 1); scode[p] = c0; }
    if (i1 < cnt) { const int p = atomicAdd(&cur[c1 & 63], 1); scode[p] = c1; }
    if (i2 < cnt) { const int p = atomicAdd(&cur[c2 & 63], 1); scode[p] = c2; }
    __syncthreads();

    if (i0 < cnt) eb[i0] = scode[i0];
    if (i1 < cnt) eb[i1] = scode[i1];
    if (i2 < cnt) eb[i2] = scode[i2];
    if (t <= BK) startsG[b * (BK + 1) + t] = starts[t];
}

// ---------------------------------------------------------------------------
// Fused aggregate + finalize, block per bucket, edges pre-sorted by local dst.
// Phase A: fill (code, w) in LDS -- 3 independent gathers/thread, no atomics,
// one barrier. Phase B: per-node register accumulation (R8 geometry: 16 lanes
// x 4 edge slots, uint2 loads -> 16 edge rows in flight per wave).
// No float atomics anywhere (R6: fp32 LDS atomicAdd = CAS loop, 359us).
// ---------------------------------------------------------------------------
__global__ __launch_bounds__(512) void gat_aggregate_kernel(
    const unsigned* __restrict__ ebuf, const int* __restrict__ startsG,
    const float* __restrict__ as_, const float* __restrict__ ad_,
    const uint2* __restrict__ xph2,   // [n*16] uint2 = 4 packed fp16 feats
    const float* __restrict__ bias,
    float* __restrict__ h, int n)
{
    __shared__ unsigned scode[CAP];
    __shared__ float    sw[CAP];
    __shared__ int startsL[BK + 1];
    __shared__ float adb[BK];

    const int b = blockIdx.x;
    const int t = threadIdx.x;
    const int lane = t & 63;
    const int wave = t >> 6;
    const int g0 = b * BK;

    if (t < BK) adb[t] = (g0 + t < n) ? ad_[g0 + t] : 0.f;
    if (t <= BK) startsL[t] = startsG[b * (BK + 1) + t];
    __syncthreads();

    const int cnt = startsL[BK];
    const unsigned* eb = ebuf + (size_t)b * CAP;

    // phase A: (code, w) into LDS; 3 independent gather chains per thread
    {
        const int i0 = t, i1 = t + 512, i2 = t + 1024;
        unsigned c0 = 0, c1 = 0, c2 = 0;
        float v0 = 0.f, v1 = 0.f, v2 = 0.f;
        if (i0 < cnt) { c0 = eb[i0]; v0 = as_[c0 >> 6]; }
        if (i1 < cnt) { c1 = eb[i1]; v1 = as_[c1 >> 6]; }
        if (i2 < cnt) { c2 = eb[i2]; v2 = as_[c2 >> 6]; }
        if (i0 < cnt) {
            float tt = v0 + adb[c0 & 63]; tt = (tt >= 0.f) ? tt : 0.2f * tt;
            scode[i0] = c0; sw[i0] = __expf(tt);
        }
        if (i1 < cnt) {
            float tt = v1 + adb[c1 & 63]; tt = (tt >= 0.f) ? tt : 0.2f * tt;
            scode[i1] = c1; sw[i1] = __expf(tt);
        }
        if (i2 < cnt) {
            float tt = v2 + adb[c2 & 63]; tt = (tt >= 0.f) ? tt : 0.2f * tt;
            scode[i2] = c2; sw[i2] = __expf(tt);
        }
    }
    __syncthreads();

    // phase B: per-node accumulation, register-only
    const int q  = lane >> 4;      // edge slot 0..3
    const int fq = lane & 15;      // feature quad: feats 4fq..4fq+3

    for (int node = wave; node < BK; node += 8) {
        const int g = g0 + node;
        if (g >= n) continue;
        const int st = startsL[node], en = startsL[node + 1];

        float a0 = 0.f, a1 = 0.f, a2 = 0.f, a3 = 0.f;
        float wsum = 0.f;

        int i = st + q;
        for (; i + 12 < en; i += 16) {
            const unsigned c0 = scode[i];
            const unsigned c1 = scode[i + 4];
            const unsigned c2 = scode[i + 8];
            const unsigned c3 = scode[i + 12];
            const float w0 = sw[i], w1 = sw[i + 4], w2 = sw[i + 8], w3 = sw[i + 12];
            const uint2 x0 = xph2[(size_t)(c0 >> 6) * 16 + fq];
            const uint2 x1 = xph2[(size_t)(c1 >> 6) * 16 + fq];
            const uint2 x2 = xph2[(size_t)(c2 >> 6) * 16 + fq];
            const uint2 x3 = xph2[(size_t)(c3 >> 6) * 16 + fq];
            const __half2 l0 = *(const __half2*)&x0.x, h0 = *(const __half2*)&x0.y;
            const __half2 l1 = *(const __half2*)&x1.x, h1 = *(const __half2*)&x1.y;
            const __half2 l2 = *(const __half2*)&x2.x, h2 = *(const __half2*)&x2.y;
            const __half2 l3 = *(const __half2*)&x3.x, h3 = *(const __half2*)&x3.y;
            a0 += w0 * __low2float(l0) + w1 * __low2float(l1)
                + w2 * __low2float(l2) + w3 * __low2float(l3);
            a1 += w0 * __high2float(l0) + w1 * __high2float(l1)
                + w2 * __high2float(l2) + w3 * __high2float(l3);
            a2 += w0 * __low2float(h0) + w1 * __low2float(h1)
                + w2 * __low2float(h2) + w3 * __low2float(h3);
            a3 += w0 * __high2float(h0) + w1 * __high2float(h1)
                + w2 * __high2float(h2) + w3 * __high2float(h3);
            wsum += (w0 + w1) + (w2 + w3);
        }
        for (; i < en; i += 4) {
            const unsigned c0 = scode[i];
            const float w0 = sw[i];
            const uint2 x0 = xph2[(size_t)(c0 >> 6) * 16 + fq];
            const __half2 l0 = *(const __half2*)&x0.x, h0 = *(const __half2*)&x0.y;
            a0 += w0 * __low2float(l0);
            a1 += w0 * __high2float(l0);
            a2 += w0 * __low2float(h0);
            a3 += w0 * __high2float(h0);
            wsum += w0;
        }

        a0   += __shfl_xor(a0, 16);   a0   += __shfl_xor(a0, 32);
        a1   += __shfl_xor(a1, 16);   a1   += __shfl_xor(a1, 32);
        a2   += __shfl_xor(a2, 16);   a2   += __shfl_xor(a2, 32);
        a3   += __shfl_xor(a3, 16);   a3   += __shfl_xor(a3, 32);
        wsum += __shfl_xor(wsum, 16); wsum += __shfl_xor(wsum, 32);

        float tt = as_[g] + adb[node];
        tt = (tt >= 0.f) ? tt : 0.2f * tt;
        const float wself = __expf(tt);
        const uint2 xg = xph2[(size_t)g * 16 + fq];
        const __half2 gl = *(const __half2*)&xg.x, gh = *(const __half2*)&xg.y;
        const float dinv = 1.f / (wsum + wself);
        const float4 b4 = *(const float4*)(bias + 4 * fq);
        float4 v;
        v.x = fmaxf((a0 + wself * __low2float(gl))  * dinv + b4.x, 0.f);
        v.y = fmaxf((a1 + wself * __high2float(gl)) * dinv + b4.y, 0.f);
        v.z = fmaxf((a2 + wself * __low2float(gh))  * dinv + b4.z, 0.f);
        v.w = fmaxf((a3 + wself * __high2float(gh)) * dinv + b4.w, 0.f);
        if (q == 0)
            *(float4*)(h + (size_t)g * FEAT + 4 * fq) = v;
    }
}

// ---------------------------------------------------------------------------
// Pool: batch sorted -> block per graph, binary-search bounds, direct sum.
// ---------------------------------------------------------------------------
__device__ __forceinline__ int lower_bound_i(const int* a, int n, int key)
{
    int lo = 0, hi = n;
    while (lo < hi) {
        const int mid = (lo + hi) >> 1;
        if (a[mid] < key) lo = mid + 1; else hi = mid;
    }
    return lo;
}

__global__ __launch_bounds__(256) void pool_kernel(
    const float* __restrict__ h, const int* __restrict__ batch,
    float* __restrict__ out, int n)
{
    const int g = blockIdx.x;
    const int lane = threadIdx.x & 63;
    const int wave = threadIdx.x >> 6;

    const int lo = lower_bound_i(batch, n, g);
    const int hi = lower_bound_i(batch, n, g + 1);

    float sum = 0.f;
    for (int i = lo + wave; i < hi; i += 4)
        sum += h[(size_t)i * FEAT + lane];

    __shared__ float part[4][FEAT];
    part[wave][lane] = sum;
    __syncthreads();
    if (wave == 0) {
        const float s = part[0][lane] + part[1][lane] + part[2][lane] + part[3][lane];
        const float c = (float)(hi - lo);
        out[(size_t)g * FEAT + lane] = s / fmaxf(c, 1.f);
    }
}

extern "C" void kernel_launch(void* const* d_in, const int* in_sizes, int n_in,
                              void* d_out, int out_size, void* d_ws, size_t ws_size,
                              hipStream_t stream)
{
    const float* x      = (const float*)d_in[0];
    const int*   ei     = (const int*)d_in[1];
    const int*   batch  = (const int*)d_in[2];
    const float* W1     = (const float*)d_in[3];
    const float* asrc1  = (const float*)d_in[4];
    const float* adst1  = (const float*)d_in[5];
    const float* b1     = (const float*)d_in[6];
    const float* W2     = (const float*)d_in[7];
    const float* asrc2  = (const float*)d_in[8];
    const float* adst2  = (const float*)d_in[9];
    const float* b2     = (const float*)d_in[10];

    const int N = in_sizes[2];          // 50000 nodes
    const int E = in_sizes[1] / 2;      // 800000 edges
    const int G = out_size / FEAT;      // 128 graphs

    const int* src = ei;
    const int* dst = ei + E;

    const int nbuck = (N + BK - 1) / BK;   // 782

    // Workspace layout
    float*    ws     = (float*)d_ws;
    unsigned* xph    = (unsigned*)ws;                      // N*32 u32 (fp16 pairs)
    float*    h      = (float*)(xph + (size_t)N * 32);     // N*64 f
    float*    as_    = h + (size_t)N * FEAT;               // N f
    float*    ad_    = as_ + N;                            // N f
    int*      bcur   = (int*)(ad_ + N);                    // nbuck i
    unsigned* ebuf   = (unsigned*)(bcur + nbuck);          // nbuck*CAP u32
    int*      startsG= (int*)(ebuf + (size_t)nbuck * CAP); // nbuck*(BK+1) i

    const int gemmBlocks = (N + 63) / 64;
    const int scatBlocks = (E + 1024 * EPT - 1) / (1024 * EPT);

    // ---- bucketed edge grouping + per-bucket sort (once, both layers) ----
    hipMemsetAsync(bcur, 0, (size_t)nbuck * sizeof(int), stream);
    bucket_scatter_kernel<<<scatBlocks, 1024, 0, stream>>>(src, dst, bcur, ebuf, E, nbuck);
    bucket_sort_kernel<<<nbuck, 512, 0, stream>>>(bcur, ebuf, startsG);

    // ---- layer 1 ----
    gemm_alpha_kernel<<<gemmBlocks, 256, 0, stream>>>(x, W1, asrc1, adst1, xph, as_, ad_, N);
    gat_aggregate_kernel<<<nbuck, 512, 0, stream>>>(ebuf, startsG, as_, ad_,
                                                    (const uint2*)xph, b1, h, N);

    // ---- layer 2 ----
    gemm_alpha_kernel<<<gemmBlocks, 256, 0, stream>>>(h, W2, asrc2, adst2, xph, as_, ad_, N);
    gat_aggregate_kernel<<<nbuck, 512, 0, stream>>>(ebuf, startsG, as_, ad_,
                                                    (const uint2*)xph, b2, h, N);

    // ---- graph mean pool ----
    pool_kernel<<<G, 256, 0, stream>>>(h, batch, (float*)d_out, N);
}